// Round 7
// baseline (74.465 us; speedup 1.0000x reference)
//
#include <hip/hip_runtime.h>

#define PIMG 1024   // H*W = 32*32
#define CCH  128    // channels
#define KG   68     // clusters incl. ghost
#define KR   64     // real clusters
#define T1   32     // pixels per block (kernel 1)

typedef float f4v __attribute__((ext_vector_type(4)));

// ---------------- Kernel 1: norms + logits + softmax ----------------
// grid: N*32 blocks (32 pixels each), 256 threads. LDS ~26 KB.
__global__ __launch_bounds__(256) void nv_assign_kernel(
    const float* __restrict__ x,       // [N,128,1024]
    const float* __restrict__ conv_w,  // [68,128]
    float* __restrict__ sa_out,        // [N,68,1024]
    float* __restrict__ rnorm_ws)      // [N*1024]
{
    __shared__ float xs[CCH * T1];   // raw x tile, [c][pix]  16 KB
    __shared__ float lg[KG * T1];    // logits→exp, [k][pix]  8.5 KB
    __shared__ float red[8 * T1];    // reduction scratch
    __shared__ float rn_l[T1];
    __shared__ float mx_l[T1];
    __shared__ float is_l[T1];

    const int t   = threadIdx.x;
    const int gp0 = blockIdx.x * T1;
    const int n   = gp0 >> 10;
    const int p0  = gp0 & 1023;

    // stage raw x tile (coalesced)
    const float* xb = x + (size_t)n * (CCH * PIMG) + p0;
    for (int i = t; i < CCH * T1; i += 256)
        xs[i] = xb[(i >> 5) * PIMG + (i & 31)];
    __syncthreads();

    // sum of squares: 8 threads per pixel, 16 channels each
    {
        int pix = t & 31, q = t >> 5;
        float s = 0.f;
        #pragma unroll
        for (int c = q * 16; c < q * 16 + 16; ++c) {
            float v = xs[c * T1 + pix];
            s += v * v;
        }
        red[q * T1 + pix] = s;
    }
    __syncthreads();
    if (t < T1) {
        float s = 0.f;
        #pragma unroll
        for (int q = 0; q < 8; ++q) s += red[q * T1 + t];
        float r = 1.0f / fmaxf(sqrtf(s), 1e-12f);
        rn_l[t] = r;
        rnorm_ws[gp0 + t] = r;
    }
    __syncthreads();

    // logits: tasks = (k-pair, pix4-group) = 34*8 = 272
    for (int task = t; task < (KG / 2) * (T1 / 4); task += 256) {
        int g  = task & 7;
        int k0 = (task >> 3) << 1;
        const float* w0 = conv_w + k0 * CCH;
        const float* w1 = w0 + CCH;
        f4v a0 = {0.f, 0.f, 0.f, 0.f}, a1 = {0.f, 0.f, 0.f, 0.f};
        #pragma unroll 8
        for (int c = 0; c < CCH; ++c) {
            f4v xv = *(const f4v*)(xs + c * T1 + g * 4);
            float wv0 = w0[c], wv1 = w1[c];
            a0 += xv * wv0;
            a1 += xv * wv1;
        }
        f4v r4 = *(const f4v*)(rn_l + g * 4);
        *(f4v*)(lg + k0 * T1 + g * 4)       = a0 * r4;
        *(f4v*)(lg + (k0 + 1) * T1 + g * 4) = a1 * r4;
    }
    __syncthreads();

    // softmax over k: 8 threads per pixel
    {
        int pix = t & 31, q = t >> 5;
        float m = -1e30f;
        for (int k = q; k < KG; k += 8) m = fmaxf(m, lg[k * T1 + pix]);
        red[q * T1 + pix] = m;
    }
    __syncthreads();
    if (t < T1) {
        float m = red[t];
        #pragma unroll
        for (int q = 1; q < 8; ++q) m = fmaxf(m, red[q * T1 + t]);
        mx_l[t] = m;
    }
    __syncthreads();
    {
        int pix = t & 31, q = t >> 5;
        float m = mx_l[pix], s = 0.f;
        for (int k = q; k < KG; k += 8) {
            float e = expf(lg[k * T1 + pix] - m);
            lg[k * T1 + pix] = e;
            s += e;
        }
        red[q * T1 + pix] = s;
    }
    __syncthreads();
    if (t < T1) {
        float s = 0.f;
        #pragma unroll
        for (int q = 0; q < 8; ++q) s += red[q * T1 + t];
        is_l[t] = 1.0f / s;
    }
    __syncthreads();

    // write soft_assign (coalesced over pix)
    for (int i = t; i < KG * T1; i += 256) {
        int k = i >> 5, pix = i & 31;
        sa_out[((size_t)n * KG + k) * PIMG + p0 + pix] = lg[i] * is_l[pix];
    }
}

// ---------------- Kernel 2: fill-style grid-stride residual ----------------
// 2048 blocks x 256 threads; thread handles 32 float4s at 8 MB stride, so the
// whole grid sweeps ONE dense linear window of out (like the fill kernel that
// hits 6.9 TB/s). Per wave (n,k,c) is uniform: centroid broadcast, x/rn/sa are
// 1 KB coalesced L1/L2-resident reads. Plain stores.
__global__ __launch_bounds__(256) void nv_resid_kernel(
    const float* __restrict__ x,          // [N,128,1024]
    const float* __restrict__ centroids,  // [68,128]
    const float* __restrict__ sa,         // [N,68,1024]
    const float* __restrict__ rnorm,      // [N,1024]
    float* __restrict__ out,              // [N,64,128,1024]
    int nf4)                              // N*64*128*256
{
    const f4v* __restrict__ xf  = (const f4v*)x;
    const f4v* __restrict__ saf = (const f4v*)sa;
    const f4v* __restrict__ rnf = (const f4v*)rnorm;
    f4v* __restrict__ of = (f4v*)out;

    const int stride = gridDim.x * 256;
    #pragma unroll 4
    for (int i = blockIdx.x * 256 + threadIdx.x; i < nf4; i += stride) {
        int pix4 = i & 255;
        int c    = (i >> 8) & 127;
        int k    = (i >> 15) & 63;
        int n    = i >> 21;
        f4v xv = xf[(n * CCH + c) * (PIMG / 4) + pix4];
        f4v rn = rnf[n * (PIMG / 4) + pix4];
        f4v a  = saf[(n * KG + k) * (PIMG / 4) + pix4];
        float ce = centroids[k * CCH + c];
        of[i] = (xv * rn - ce) * a;
    }
}

extern "C" void kernel_launch(void* const* d_in, const int* in_sizes, int n_in,
                              void* d_out, int out_size, void* d_ws, size_t ws_size,
                              hipStream_t stream) {
    const float* x         = (const float*)d_in[0];
    const float* conv_w    = (const float*)d_in[1];
    const float* centroids = (const float*)d_in[2];

    const int N = in_sizes[0] / (CCH * PIMG);   // 8

    float* out    = (float*)d_out;
    float* sa_out = out + (size_t)N * KR * CCH * PIMG;  // second tuple element
    float* rnorm  = (float*)d_ws;                        // N*1024 floats

    const int nf4 = N * KR * CCH * (PIMG / 4);

    nv_assign_kernel<<<N * (PIMG / T1), 256, 0, stream>>>(x, conv_w, sa_out, rnorm);
    nv_resid_kernel<<<2048, 256, 0, stream>>>(x, centroids, sa_out, rnorm, out, nf4);
}